// Round 4
// baseline (92.558 us; speedup 1.0000x reference)
//
#include <hip/hip_runtime.h>
#include <hip/hip_cooperative_groups.h>

// Match XLA's elementwise f32 exactly: no FMA contraction on the decision path.
#pragma clang fp contract(off)

namespace cg = cooperative_groups;

#define N_BOX   10647
#define N_CLS   80
#define ROW     85
#define CONF_T  0.8f
#define NMS_T   0.4f
#define NEGV    -1000000000.0f
#define KMAX    256       // max boxes per class (expected ~27)
#define OUT_N   3000
#define SURV_N  4096      // survivors cap (expected ~2000)
#define NBLK    192
#define NTHR    256
#define ROWS_PB ((N_BOX + NBLK - 1) / NBLK)   // 56 rows/block
#define N_CTR   81        // counters[0..79]=per-class, [80]=survivors

struct Rec { float x1, y1, x2, y2, score, conf; int idx, pad; };

__global__ __launch_bounds__(NTHR) void k_fused(const float* __restrict__ det,
                                                float* __restrict__ out,
                                                int* __restrict__ counters,
                                                Rec* __restrict__ bins,
                                                float* __restrict__ surv) {
    cg::grid_group grid = cg::this_grid();
    __shared__ float lds[ROWS_PB * ROW];   // 19040 B, reused across phases
    __shared__ int nkeep, base;
    const int tid  = threadIdx.x;
    const int bid  = blockIdx.x;
    const int gidx = bid * NTHR + tid;

    // ---------------- Phase A: init ----------------
    if (gidx < OUT_N) out[gidx] = NEGV;
    if (gidx < N_CTR) counters[gidx] = 0;
    grid.sync();

    // ---------------- Phase B: filter + argmax + bin (batch 0) ----------------
    {
        const int row0 = bid * ROWS_PB;
        int nrows = N_BOX - row0; if (nrows > ROWS_PB) nrows = ROWS_PB;
        if (nrows > 0) {
            const int nflt = nrows * ROW;
            const float* src = det + (size_t)row0 * ROW;   // 16B-aligned: 56*85*4=19040
            const int n4 = nflt >> 2;
            float4* l4 = (float4*)lds;
            const float4* s4 = (const float4*)src;
            for (int j = tid; j < n4; j += NTHR) l4[j] = s4[j];
            for (int j = (n4 << 2) + tid; j < nflt; j += NTHR) lds[j] = src[j];
            __syncthreads();
            if (tid < nrows) {
                const float* p = lds + tid * ROW;
                float obj = p[4];
                if (obj >= CONF_T) {
                    float cx = p[0], cy = p[1], w = p[2], h = p[3];
                    float hw = w / 2.0f, hh = h / 2.0f;
                    // first-argmax over 80 classes (strict > keeps first = jnp.argmax)
                    float best = p[5]; int bcls = 0;
                    for (int c = 1; c < N_CLS; ++c) {
                        float v = p[5 + c];
                        if (v > best) { best = v; bcls = c; }
                    }
                    int pos = atomicAdd(&counters[bcls], 1);
                    if (pos < KMAX) {
                        Rec r;
                        r.x1 = cx - hw; r.y1 = cy - hh; r.x2 = cx + hw; r.y2 = cy + hh;
                        r.score = obj * best; r.conf = best; r.idx = row0 + tid; r.pad = 0;
                        bins[bcls * KMAX + pos] = r;
                    }
                }
            }
        }
    }
    grid.sync();

    // ---------------- Phase C: per-class NMS (blocks 0..79) ----------------
    if (bid < N_CLS) {
        // carve NMS arrays out of the staging LDS (9.25 KB < 19 KB)
        float* rsc   = lds;                        // [KMAX]
        int*   ridx  = (int*)(lds + KMAX);         // [KMAX]
        float* sx1   = lds + 2 * KMAX;
        float* sy1   = lds + 3 * KMAX;
        float* sx2   = lds + 4 * KMAX;
        float* sy2   = lds + 5 * KMAX;
        float* scf   = lds + 6 * KMAX;
        float* keepc = lds + 7 * KMAX;
        unsigned char* alive = (unsigned char*)(lds + 8 * KMAX);

        const int c = bid;
        if (tid == 0) nkeep = 0;
        int k = counters[c]; if (k > KMAX) k = KMAX;

        for (int i = tid; i < k; i += NTHR) {
            const Rec r = bins[c * KMAX + i];
            rsc[i] = r.score; ridx[i] = r.idx;
        }
        __syncthreads();

        // rank = #{j : score[j] > score[i] or (==, idx[j] < idx[i])} -> stable desc
        for (int i = tid; i < k; i += NTHR) {
            float s = rsc[i]; int id = ridx[i]; int r = 0;
            for (int j = 0; j < k; ++j) {
                float sj = rsc[j];
                r += (sj > s) || (sj == s && ridx[j] < id);
            }
            const Rec rec = bins[c * KMAX + i];
            sx1[r] = rec.x1; sy1[r] = rec.y1; sx2[r] = rec.x2; sy2[r] = rec.y2;
            scf[r] = rec.conf;
            alive[r] = 1;
        }
        __syncthreads();

        // greedy NMS with the reference's exact IoU arithmetic
        for (int i = 0; i < k; ++i) {
            bool a = (alive[i] != 0);
            __syncthreads();          // all read alive[i] before thread0 clears it
            if (a) {
                if (tid == 0) { keepc[nkeep++] = scf[i]; alive[i] = 0; }
                float bx1 = sx1[i], by1 = sy1[i], bx2 = sx2[i], by2 = sy2[i];
                float a1 = ((bx2 - bx1) + 1.0f) * ((by2 - by1) + 1.0f);
                for (int j = i + 1 + tid; j < k; j += NTHR) {
                    if (!alive[j]) continue;
                    float ix1 = fmaxf(bx1, sx1[j]);
                    float iy1 = fmaxf(by1, sy1[j]);
                    float ix2 = fminf(bx2, sx2[j]);
                    float iy2 = fminf(by2, sy2[j]);
                    float iw = fmaxf((ix2 - ix1) + 1.0f, 0.0f);
                    float ih = fmaxf((iy2 - iy1) + 1.0f, 0.0f);
                    float inter = iw * ih;
                    float a2 = ((sx2[j] - sx1[j]) + 1.0f) * ((sy2[j] - sy1[j]) + 1.0f);
                    float den = ((a1 + a2) - inter) + 1e-16f;
                    if (inter / den > NMS_T) alive[j] = 0;
                }
            }
            __syncthreads();          // suppression visible before next iteration
        }

        if (tid == 0) base = atomicAdd(&counters[80], nkeep);
        __syncthreads();
        int nb = nkeep, b = base;
        for (int i = tid; i < nb; i += NTHR) {
            int o = b + i;
            if (o < SURV_N) surv[o] = keepc[i];
        }
    }
    grid.sync();

    // ---------------- Phase D: rank-scatter (one wave per element) ----------------
    {
        int m = counters[80]; if (m > SURV_N) m = SURV_N;
        const int lane = tid & 63;
        const int wid  = gidx >> 6;              // 0 .. NBLK*4-1 (768 waves)
        for (int g = wid; g < m; g += NBLK * (NTHR / 64)) {
            const float v = surv[g];
            int cnt = 0;
            for (int j = lane; j < m; j += 64) {
                float sj = surv[j];
                cnt += (sj > v) || (sj == v && j < g);
            }
            #pragma unroll
            for (int off = 32; off > 0; off >>= 1) cnt += __shfl_down(cnt, off, 64);
            if (lane == 0 && cnt < OUT_N) out[cnt] = v;
        }
    }
}

extern "C" void kernel_launch(void* const* d_in, const int* in_sizes, int n_in,
                              void* d_out, int out_size, void* d_ws, size_t ws_size,
                              hipStream_t stream) {
    const float* det = (const float*)d_in[0];
    float* out = (float*)d_out;

    int*   counters = (int*)d_ws;                                      // 81 ints
    Rec*   bins     = (Rec*)((char*)d_ws + 512);                       // 80*256*32 B
    float* surv     = (float*)((char*)d_ws + 512 + N_CLS * KMAX * sizeof(Rec));

    void* args[] = { (void*)&det, (void*)&out, (void*)&counters,
                     (void*)&bins, (void*)&surv };
    hipLaunchCooperativeKernel((const void*)k_fused, dim3(NBLK), dim3(NTHR),
                               args, 0, stream);
}

// Round 5
// 66.282 us; speedup vs baseline: 1.3964x; 1.3964x over previous
//
#include <hip/hip_runtime.h>

// Match XLA's elementwise f32 exactly: no FMA contraction on the decision path.
#pragma clang fp contract(off)

#define N_BOX   10647
#define N_CLS   80
#define ROW     85
#define CONF_T  0.8f
#define NMS_T   0.4f
#define NEGV    -1000000000.0f
#define KMAX    256       // max boxes per class (expected ~27)
#define OUT_N   3000
#define SURV_N  4096      // survivors cap (expected ~2000)
#define NBLK    192
#define NTHR    256
#define ROWS_PB ((N_BOX + NBLK - 1) / NBLK)   // 56 rows/block
#define CTR_SURV 80       // counters[80] = survivor count
#define CTR_BAR  81       // counters[81] = grid barrier

struct Rec { float x1, y1, x2, y2, score, conf; int idx, pad; };

// Software grid barrier: release (wb L2) -> arrive -> relaxed spin -> acquire (inv).
// Co-residency: 192 blocks x 4 waves, 19KB LDS, 20 VGPR -> 1+ block/CU on 256 CUs.
// Bounded spin: on failure we produce wrong output (loud) instead of hanging.
__device__ __forceinline__ void grid_bar(int* bar, int target) {
    __syncthreads();                       // all block stores at L2 (vmcnt drained)
    if (threadIdx.x == 0) {
        __threadfence();                   // release: push block's stores to MALL
        __hip_atomic_fetch_add(bar, 1, __ATOMIC_RELAXED, __HIP_MEMORY_SCOPE_AGENT);
        long guard = 0;
        while (__hip_atomic_load(bar, __ATOMIC_RELAXED, __HIP_MEMORY_SCOPE_AGENT) < target) {
            __builtin_amdgcn_s_sleep(2);
            if (++guard > (1L << 26)) break;
        }
        __threadfence();                   // acquire: invalidate stale L1/L2
    }
    __syncthreads();
}

__global__ __launch_bounds__(NTHR) void k_fused(const float* __restrict__ det,
                                                float* __restrict__ out,
                                                int* counters,
                                                Rec* __restrict__ bins,
                                                float* __restrict__ surv) {
    __shared__ float lds[ROWS_PB * ROW];   // 19040 B, reused across phases
    __shared__ int nkeep, base;
    const int tid  = threadIdx.x;
    const int bid  = blockIdx.x;
    const int gidx = bid * NTHR + tid;
    int* bar = counters + CTR_BAR;

    // ---------------- Phase B: filter + argmax + bin (batch 0) ----------------
    {
        const int row0 = bid * ROWS_PB;
        int nrows = N_BOX - row0; if (nrows > ROWS_PB) nrows = ROWS_PB;
        if (nrows > 0) {
            const int nflt = nrows * ROW;
            const float* src = det + (size_t)row0 * ROW;   // 19040*bid: 16B aligned
            const int n4 = nflt >> 2;
            float4* l4 = (float4*)lds;
            const float4* s4 = (const float4*)src;
            for (int j = tid; j < n4; j += NTHR) l4[j] = s4[j];
            for (int j = (n4 << 2) + tid; j < nflt; j += NTHR) lds[j] = src[j];
            __syncthreads();
            if (tid < nrows) {
                const float* p = lds + tid * ROW;
                float obj = p[4];
                if (obj >= CONF_T) {
                    float cx = p[0], cy = p[1], w = p[2], h = p[3];
                    float hw = w / 2.0f, hh = h / 2.0f;
                    // first-argmax over 80 classes (strict > keeps first = jnp.argmax)
                    float best = p[5]; int bcls = 0;
                    for (int c = 1; c < N_CLS; ++c) {
                        float v = p[5 + c];
                        if (v > best) { best = v; bcls = c; }
                    }
                    int pos = atomicAdd(&counters[bcls], 1);
                    if (pos < KMAX) {
                        Rec r;
                        r.x1 = cx - hw; r.y1 = cy - hh; r.x2 = cx + hw; r.y2 = cy + hh;
                        r.score = obj * best; r.conf = best; r.idx = row0 + tid; r.pad = 0;
                        bins[bcls * KMAX + pos] = r;
                    }
                }
            }
        }
    }
    grid_bar(bar, NBLK);

    // ---------------- Phase C: per-class NMS (blocks 0..79) ----------------
    if (bid < N_CLS) {
        // carve NMS arrays out of the staging LDS (9.25 KB < 19 KB)
        float* rsc   = lds;                        // [KMAX]
        int*   ridx  = (int*)(lds + KMAX);         // [KMAX]
        float* sx1   = lds + 2 * KMAX;
        float* sy1   = lds + 3 * KMAX;
        float* sx2   = lds + 4 * KMAX;
        float* sy2   = lds + 5 * KMAX;
        float* scf   = lds + 6 * KMAX;
        float* keepc = lds + 7 * KMAX;
        unsigned char* alive = (unsigned char*)(lds + 8 * KMAX);

        const int c = bid;
        if (tid == 0) nkeep = 0;
        int k = counters[c]; if (k > KMAX) k = KMAX;

        for (int i = tid; i < k; i += NTHR) {
            const Rec r = bins[c * KMAX + i];
            rsc[i] = r.score; ridx[i] = r.idx;
        }
        __syncthreads();

        // rank = #{j : score[j] > score[i] or (==, idx[j] < idx[i])} -> stable desc
        for (int i = tid; i < k; i += NTHR) {
            float s = rsc[i]; int id = ridx[i]; int r = 0;
            for (int j = 0; j < k; ++j) {
                float sj = rsc[j];
                r += (sj > s) || (sj == s && ridx[j] < id);
            }
            const Rec rec = bins[c * KMAX + i];
            sx1[r] = rec.x1; sy1[r] = rec.y1; sx2[r] = rec.x2; sy2[r] = rec.y2;
            scf[r] = rec.conf;
            alive[r] = 1;
        }
        __syncthreads();

        // greedy NMS with the reference's exact IoU arithmetic
        for (int i = 0; i < k; ++i) {
            bool a = (alive[i] != 0);
            __syncthreads();          // all read alive[i] before thread0 clears it
            if (a) {
                if (tid == 0) { keepc[nkeep++] = scf[i]; alive[i] = 0; }
                float bx1 = sx1[i], by1 = sy1[i], bx2 = sx2[i], by2 = sy2[i];
                float a1 = ((bx2 - bx1) + 1.0f) * ((by2 - by1) + 1.0f);
                for (int j = i + 1 + tid; j < k; j += NTHR) {
                    if (!alive[j]) continue;
                    float ix1 = fmaxf(bx1, sx1[j]);
                    float iy1 = fmaxf(by1, sy1[j]);
                    float ix2 = fminf(bx2, sx2[j]);
                    float iy2 = fminf(by2, sy2[j]);
                    float iw = fmaxf((ix2 - ix1) + 1.0f, 0.0f);
                    float ih = fmaxf((iy2 - iy1) + 1.0f, 0.0f);
                    float inter = iw * ih;
                    float a2 = ((sx2[j] - sx1[j]) + 1.0f) * ((sy2[j] - sy1[j]) + 1.0f);
                    float den = ((a1 + a2) - inter) + 1e-16f;
                    if (inter / den > NMS_T) alive[j] = 0;
                }
            }
            __syncthreads();          // suppression visible before next iteration
        }

        if (tid == 0) base = atomicAdd(&counters[CTR_SURV], nkeep);
        __syncthreads();
        int nb = nkeep, b = base;
        for (int i = tid; i < nb; i += NTHR) {
            int o = b + i;
            if (o < SURV_N) surv[o] = keepc[i];
        }
    }
    grid_bar(bar, 2 * NBLK);

    // ---------------- Phase D: rank-scatter + tail fill ----------------
    // Ranks (ties broken by index) are a permutation of 0..m-1, so the scatter
    // covers out[0..m-1] exactly once; fill out[m..OUT_N-1] with NEG.
    {
        int m = counters[CTR_SURV]; if (m > SURV_N) m = SURV_N;
        const int lane = tid & 63;
        const int wid  = gidx >> 6;                      // 0..767
        for (int g = wid; g < m; g += NBLK * (NTHR / 64)) {
            const float v = surv[g];
            int cnt = 0;
            for (int j = lane; j < m; j += 64) {
                float sj = surv[j];
                cnt += (sj > v) || (sj == v && j < g);
            }
            #pragma unroll
            for (int off = 32; off > 0; off >>= 1) cnt += __shfl_down(cnt, off, 64);
            if (lane == 0 && cnt < OUT_N) out[cnt] = v;
        }
        for (int i = m + gidx; i < OUT_N; i += NBLK * NTHR) out[i] = NEGV;
    }
}

extern "C" void kernel_launch(void* const* d_in, const int* in_sizes, int n_in,
                              void* d_out, int out_size, void* d_ws, size_t ws_size,
                              hipStream_t stream) {
    const float* det = (const float*)d_in[0];
    float* out = (float*)d_out;

    int*   counters = (int*)d_ws;                                      // 82 ints
    Rec*   bins     = (Rec*)((char*)d_ws + 512);                       // 80*256*32 B
    float* surv     = (float*)((char*)d_ws + 512 + N_CLS * KMAX * sizeof(Rec));

    hipMemsetAsync(d_ws, 0, 512, stream);   // counters + barrier, every call
    hipLaunchKernelGGL(k_fused, dim3(NBLK), dim3(NTHR), 0, stream,
                       det, out, counters, bins, surv);
}

// Round 6
// 49.147 us; speedup vs baseline: 1.8833x; 1.3486x over previous
//
#include <hip/hip_runtime.h>

// Match XLA's elementwise f32 exactly: no FMA contraction on the decision path.
#pragma clang fp contract(off)

#define N_BOX   10647
#define N_CLS   80
#define ROW     85
#define CONF_T  0.8f
#define NMS_T   0.4f
#define NEGV    -1000000000.0f
#define KMAX    256       // max boxes per class (expected ~27)
#define OUT_N   3000
#define SURV_N  4096      // survivors cap (expected ~2000)
#define NBLK    192
#define NTHR    256
#define ROWS_PB ((N_BOX + NBLK - 1) / NBLK)   // 56 rows/block
#define CTR_SURV 80       // counters[80] = survivor count
#define CTR_BAR  120      // counters[120] = grid barrier (own 128B cacheline)

// MALL-coherent (cross-XCD safe, L2-bypassing) accessors.
#define AT_LDF(p)   __hip_atomic_load((p),  __ATOMIC_RELAXED, __HIP_MEMORY_SCOPE_AGENT)
#define AT_LDI(p)   __hip_atomic_load((p),  __ATOMIC_RELAXED, __HIP_MEMORY_SCOPE_AGENT)
#define AT_STF(p,v) __hip_atomic_store((p), (v), __ATOMIC_RELAXED, __HIP_MEMORY_SCOPE_AGENT)
#define AT_STI(p,v) __hip_atomic_store((p), (v), __ATOMIC_RELAXED, __HIP_MEMORY_SCOPE_AGENT)

// Fence-free grid barrier. All cross-block data moves via sc1 (MALL) accesses,
// so no L2 writeback/invalidate is needed. __syncthreads() drains vmcnt, so
// every sc1 store of this block is at the coherence point before arrival.
__device__ __forceinline__ void grid_bar(int* bar, int target) {
    __syncthreads();
    if (threadIdx.x == 0) {
        __builtin_amdgcn_s_waitcnt(0);   // belt-and-braces: all counters 0
        __hip_atomic_fetch_add(bar, 1, __ATOMIC_RELAXED, __HIP_MEMORY_SCOPE_AGENT);
        long guard = 0;
        while (__hip_atomic_load(bar, __ATOMIC_RELAXED, __HIP_MEMORY_SCOPE_AGENT) < target) {
            __builtin_amdgcn_s_sleep(2);
            if (++guard > (1L << 26)) break;   // fail loud, never hang
        }
    }
    __syncthreads();
}

__global__ __launch_bounds__(NTHR) void k_fused(const float* __restrict__ det,
                                                float* __restrict__ out,
                                                int* counters,
                                                float* bx1, float* by1,
                                                float* bx2, float* by2,
                                                float* bsc, float* bcf, int* bix,
                                                float* surv) {
    __shared__ float lds[ROWS_PB * ROW];   // 19040 B, reused across phases
    __shared__ int nkeep, base;
    const int tid  = threadIdx.x;
    const int bid  = blockIdx.x;
    const int gidx = bid * NTHR + tid;
    int* bar = counters + CTR_BAR;

    // ---------------- Phase B: filter + argmax + bin (batch 0) ----------------
    {
        const int row0 = bid * ROWS_PB;
        int nrows = N_BOX - row0; if (nrows > ROWS_PB) nrows = ROWS_PB;
        if (nrows > 0) {
            const int nflt = nrows * ROW;
            const float* src = det + (size_t)row0 * ROW;   // 19040*bid: 16B aligned
            const int n4 = nflt >> 2;
            float4* l4 = (float4*)lds;
            const float4* s4 = (const float4*)src;
            for (int j = tid; j < n4; j += NTHR) l4[j] = s4[j];
            for (int j = (n4 << 2) + tid; j < nflt; j += NTHR) lds[j] = src[j];
            __syncthreads();
            if (tid < nrows) {
                const float* p = lds + tid * ROW;
                float obj = p[4];
                if (obj >= CONF_T) {
                    float cx = p[0], cy = p[1], w = p[2], h = p[3];
                    float hw = w / 2.0f, hh = h / 2.0f;
                    // first-argmax over 80 classes (strict > keeps first = jnp.argmax)
                    float best = p[5]; int bcls = 0;
                    for (int c = 1; c < N_CLS; ++c) {
                        float v = p[5 + c];
                        if (v > best) { best = v; bcls = c; }
                    }
                    int pos = atomicAdd(&counters[bcls], 1);   // agent scope (MALL)
                    if (pos < KMAX) {
                        int o = bcls * KMAX + pos;
                        AT_STF(&bx1[o], cx - hw); AT_STF(&by1[o], cy - hh);
                        AT_STF(&bx2[o], cx + hw); AT_STF(&by2[o], cy + hh);
                        AT_STF(&bsc[o], obj * best); AT_STF(&bcf[o], best);
                        AT_STI(&bix[o], row0 + tid);
                    }
                }
            }
        }
    }
    grid_bar(bar, NBLK);

    // ---------------- Phase C: per-class NMS (blocks 0..79) ----------------
    if (bid < N_CLS) {
        // carve NMS arrays out of the staging LDS (9.25 KB < 19 KB)
        float* rsc   = lds;                        // [KMAX]
        int*   ridx  = (int*)(lds + KMAX);         // [KMAX]
        float* sx1   = lds + 2 * KMAX;
        float* sy1   = lds + 3 * KMAX;
        float* sx2   = lds + 4 * KMAX;
        float* sy2   = lds + 5 * KMAX;
        float* scf   = lds + 6 * KMAX;
        float* keepc = lds + 7 * KMAX;
        unsigned char* alive = (unsigned char*)(lds + 8 * KMAX);

        const int c = bid;
        if (tid == 0) nkeep = 0;
        int k = AT_LDI(&counters[c]); if (k > KMAX) k = KMAX;

        for (int i = tid; i < k; i += NTHR) {
            rsc[i] = AT_LDF(&bsc[c * KMAX + i]);
            ridx[i] = AT_LDI(&bix[c * KMAX + i]);
        }
        __syncthreads();

        // rank = #{j : score[j] > score[i] or (==, idx[j] < idx[i])} -> stable desc
        for (int i = tid; i < k; i += NTHR) {
            float s = rsc[i]; int id = ridx[i]; int r = 0;
            for (int j = 0; j < k; ++j) {
                float sj = rsc[j];
                r += (sj > s) || (sj == s && ridx[j] < id);
            }
            int o = c * KMAX + i;
            sx1[r] = AT_LDF(&bx1[o]); sy1[r] = AT_LDF(&by1[o]);
            sx2[r] = AT_LDF(&bx2[o]); sy2[r] = AT_LDF(&by2[o]);
            scf[r] = AT_LDF(&bcf[o]);
            alive[r] = 1;
        }
        __syncthreads();

        // greedy NMS with the reference's exact IoU arithmetic
        for (int i = 0; i < k; ++i) {
            bool a = (alive[i] != 0);
            __syncthreads();          // all read alive[i] before thread0 clears it
            if (a) {
                if (tid == 0) { keepc[nkeep++] = scf[i]; alive[i] = 0; }
                float px1 = sx1[i], py1 = sy1[i], px2 = sx2[i], py2 = sy2[i];
                float a1 = ((px2 - px1) + 1.0f) * ((py2 - py1) + 1.0f);
                for (int j = i + 1 + tid; j < k; j += NTHR) {
                    if (!alive[j]) continue;
                    float ix1 = fmaxf(px1, sx1[j]);
                    float iy1 = fmaxf(py1, sy1[j]);
                    float ix2 = fminf(px2, sx2[j]);
                    float iy2 = fminf(py2, sy2[j]);
                    float iw = fmaxf((ix2 - ix1) + 1.0f, 0.0f);
                    float ih = fmaxf((iy2 - iy1) + 1.0f, 0.0f);
                    float inter = iw * ih;
                    float a2 = ((sx2[j] - sx1[j]) + 1.0f) * ((sy2[j] - sy1[j]) + 1.0f);
                    float den = ((a1 + a2) - inter) + 1e-16f;
                    if (inter / den > NMS_T) alive[j] = 0;
                }
            }
            __syncthreads();          // suppression visible before next iteration
        }

        if (tid == 0) base = atomicAdd(&counters[CTR_SURV], nkeep);
        __syncthreads();
        int nb = nkeep, b = base;
        for (int i = tid; i < nb; i += NTHR) {
            int o = b + i;
            if (o < SURV_N) AT_STF(&surv[o], keepc[i]);
        }
    }
    grid_bar(bar, 2 * NBLK);

    // ---------------- Phase D: rank-scatter + tail fill ----------------
    // Ranks (ties broken by surv index) form a permutation of 0..m-1, so the
    // scatter covers out[0..m-1] exactly once; fill out[m..OUT_N-1] with NEG.
    {
        int m = AT_LDI(&counters[CTR_SURV]); if (m > SURV_N) m = SURV_N;
        float* slds = lds;                         // reuse staging LDS (16KB max)
        for (int i = tid; i < m; i += NTHR) slds[i] = AT_LDF(&surv[i]);
        __syncthreads();

        const int lane = tid & 63;
        const int wid  = gidx >> 6;                      // 0..767
        for (int g = wid; g < m; g += NBLK * (NTHR / 64)) {
            const float v = slds[g];
            int cnt = 0;
            for (int j = lane; j < m; j += 64) {
                float sj = slds[j];
                cnt += (sj > v) || (sj == v && j < g);
            }
            #pragma unroll
            for (int off = 32; off > 0; off >>= 1) cnt += __shfl_down(cnt, off, 64);
            if (lane == 0 && cnt < OUT_N) out[cnt] = v;
        }
        for (int i = m + gidx; i < OUT_N; i += NBLK * NTHR) out[i] = NEGV;
    }
}

extern "C" void kernel_launch(void* const* d_in, const int* in_sizes, int n_in,
                              void* d_out, int out_size, void* d_ws, size_t ws_size,
                              hipStream_t stream) {
    const float* det = (const float*)d_in[0];
    float* out = (float*)d_out;

    const size_t NB = (size_t)N_CLS * KMAX;     // 20480 elements per SoA array
    char* p = (char*)d_ws;
    int*   counters = (int*)p;        p += 512;            // 128 ints (incl. barrier)
    float* bx1 = (float*)p;           p += NB * 4;
    float* by1 = (float*)p;           p += NB * 4;
    float* bx2 = (float*)p;           p += NB * 4;
    float* by2 = (float*)p;           p += NB * 4;
    float* bsc = (float*)p;           p += NB * 4;
    float* bcf = (float*)p;           p += NB * 4;
    int*   bix = (int*)p;             p += NB * 4;
    float* surv = (float*)p;

    hipMemsetAsync(d_ws, 0, 512, stream);   // counters + barrier, every call
    hipLaunchKernelGGL(k_fused, dim3(NBLK), dim3(NTHR), 0, stream,
                       det, out, counters,
                       bx1, by1, bx2, by2, bsc, bcf, bix, surv);
}

// Round 7
// 48.253 us; speedup vs baseline: 1.9182x; 1.0185x over previous
//
#include <hip/hip_runtime.h>

// Match XLA's elementwise f32 exactly: no FMA contraction on the decision path.
#pragma clang fp contract(off)

#define N_BOX   10647
#define N_CLS   80
#define ROW     85
#define CONF_T  0.8f
#define NMS_T   0.4f
#define NEGV    -1000000000.0f
#define KMAX    256       // max boxes per class (expected ~27)
#define OUT_N   3000
#define SURV_N  4096      // survivors cap (expected ~2000)
#define NBLK    80        // == N_CLS: one block per class in every phase
#define NTHR    256
#define ROWS_PB 136       // 80*136 >= 10647; 136*85*4 = 46240 B LDS, 16B-aligned
#define CTR_STRIDE 32     // one counter per 128B cacheline (kills MALL atomic serialization)
#define CTR_SURV (80 * CTR_STRIDE)
#define CTR_BAR  (81 * CTR_STRIDE)
#define CTR_BYTES (82 * 128)

typedef unsigned long long u64;
typedef unsigned int u32;

// MALL-coherent (cross-XCD safe, L2-bypassing) accessors.
#define AT_LD64(p)   __hip_atomic_load((p),  __ATOMIC_RELAXED, __HIP_MEMORY_SCOPE_AGENT)
#define AT_ST64(p,v) __hip_atomic_store((p), (v), __ATOMIC_RELAXED, __HIP_MEMORY_SCOPE_AGENT)
#define AT_LD32(p)   __hip_atomic_load((p),  __ATOMIC_RELAXED, __HIP_MEMORY_SCOPE_AGENT)
#define AT_ST32(p,v) __hip_atomic_store((p), (v), __ATOMIC_RELAXED, __HIP_MEMORY_SCOPE_AGENT)
#define AT_LDF(p)    __hip_atomic_load((p),  __ATOMIC_RELAXED, __HIP_MEMORY_SCOPE_AGENT)
#define AT_STF(p,v)  __hip_atomic_store((p), (v), __ATOMIC_RELAXED, __HIP_MEMORY_SCOPE_AGENT)

__device__ __forceinline__ u64 pack_ff(float a, float b) {
    union { float f[2]; u64 u; } x; x.f[0] = a; x.f[1] = b; return x.u;
}
__device__ __forceinline__ u64 pack_fi(float a, int b) {
    union { struct { float f; int i; } s; u64 u; } x; x.s.f = a; x.s.i = b; return x.u;
}
__device__ __forceinline__ float lo_f(u64 v) { union { u64 u; float f[2]; } x; x.u = v; return x.f[0]; }
__device__ __forceinline__ float hi_f(u64 v) { union { u64 u; float f[2]; } x; x.u = v; return x.f[1]; }
__device__ __forceinline__ int   hi_i(u64 v) { union { u64 u; int i[2]; } x; x.u = v; return x.i[1]; }

// Fence-free grid barrier: sc1 data is already at MALL when __syncthreads
// drains vmcnt, so arrival is one relaxed agent fetch_add; exit is a relaxed
// poll. Bounded spin: fails loud, never hangs.
__device__ __forceinline__ void grid_bar(int* bar, int target) {
    __syncthreads();
    if (threadIdx.x == 0) {
        __builtin_amdgcn_s_waitcnt(0);
        __hip_atomic_fetch_add(bar, 1, __ATOMIC_RELAXED, __HIP_MEMORY_SCOPE_AGENT);
        long guard = 0;
        while (__hip_atomic_load(bar, __ATOMIC_RELAXED, __HIP_MEMORY_SCOPE_AGENT) < target) {
            __builtin_amdgcn_s_sleep(2);
            if (++guard > (1L << 26)) break;
        }
    }
    __syncthreads();
}

__global__ __launch_bounds__(NTHR) void k_fused(const float* __restrict__ det,
                                                float* __restrict__ out,
                                                int* counters,
                                                u64* pA, u64* pB, u64* pS, u32* pC,
                                                float* surv) {
    __shared__ float lds[ROWS_PB * ROW];   // 46240 B, reused across phases
    __shared__ int nkeep, base;
    const int tid  = threadIdx.x;
    const int bid  = blockIdx.x;
    const int gidx = bid * NTHR + tid;
    int* bar = counters + CTR_BAR;

    // ---------------- Phase B: filter + argmax + bin (batch 0) ----------------
    {
        const int row0 = bid * ROWS_PB;
        int nrows = N_BOX - row0;
        if (nrows > ROWS_PB) nrows = ROWS_PB;
        if (nrows > 0) {
            const int nflt = nrows * ROW;
            const float* src = det + (size_t)row0 * ROW;  // 46240*bid bytes: 16B aligned
            const int n4 = nflt >> 2;
            float4* l4 = (float4*)lds;
            const float4* s4 = (const float4*)src;
            #pragma unroll 4
            for (int j = tid; j < n4; j += NTHR) l4[j] = s4[j];
            for (int j = (n4 << 2) + tid; j < nflt; j += NTHR) lds[j] = src[j];
            __syncthreads();
            if (tid < nrows) {
                const float* p = lds + tid * ROW;
                float obj = p[4];
                if (obj >= CONF_T) {
                    float cx = p[0], cy = p[1], w = p[2], h = p[3];
                    float hw = w / 2.0f, hh = h / 2.0f;
                    // first-argmax over 80 classes (strict > keeps first = jnp.argmax)
                    float best = p[5]; int bcls = 0;
                    for (int c = 1; c < N_CLS; ++c) {
                        float v = p[5 + c];
                        if (v > best) { best = v; bcls = c; }
                    }
                    int pos = atomicAdd(&counters[bcls * CTR_STRIDE], 1);  // own cacheline
                    if (pos < KMAX) {
                        int o = bcls * KMAX + pos;
                        AT_ST64(&pA[o], pack_ff(cx - hw, cy - hh));
                        AT_ST64(&pB[o], pack_ff(cx + hw, cy + hh));
                        AT_ST64(&pS[o], pack_fi(obj * best, row0 + tid));
                        AT_ST32(&pC[o], __float_as_uint(best));
                    }
                }
            }
        }
    }
    grid_bar(bar, NBLK);

    // ---------------- Phase C: per-class NMS (block == class) ----------------
    {
        // carve NMS arrays out of the staging LDS (9.25 KB < 46 KB)
        float* rsc   = lds;                        // [KMAX]
        int*   ridx  = (int*)(lds + KMAX);         // [KMAX]
        float* sx1   = lds + 2 * KMAX;
        float* sy1   = lds + 3 * KMAX;
        float* sx2   = lds + 4 * KMAX;
        float* sy2   = lds + 5 * KMAX;
        float* scf   = lds + 6 * KMAX;
        float* keepc = lds + 7 * KMAX;
        unsigned char* alive = (unsigned char*)(lds + 8 * KMAX);

        const int c = bid;
        if (tid == 0) nkeep = 0;
        int k = AT_LD32((u32*)&counters[c * CTR_STRIDE]);
        if (k > KMAX) k = KMAX;

        for (int i = tid; i < k; i += NTHR) {
            u64 si = AT_LD64(&pS[c * KMAX + i]);
            rsc[i] = lo_f(si); ridx[i] = hi_i(si);
        }
        __syncthreads();

        // rank = #{j : score[j] > score[i] or (==, idx[j] < idx[i])} -> stable desc
        for (int i = tid; i < k; i += NTHR) {
            float s = rsc[i]; int id = ridx[i]; int r = 0;
            for (int j = 0; j < k; ++j) {
                float sj = rsc[j];
                r += (sj > s) || (sj == s && ridx[j] < id);
            }
            int o = c * KMAX + i;
            u64 a = AT_LD64(&pA[o]);
            u64 b = AT_LD64(&pB[o]);
            sx1[r] = lo_f(a); sy1[r] = hi_f(a);
            sx2[r] = lo_f(b); sy2[r] = hi_f(b);
            scf[r] = __uint_as_float(AT_LD32(&pC[o]));
            alive[r] = 1;
        }
        __syncthreads();

        // greedy NMS with the reference's exact IoU arithmetic
        for (int i = 0; i < k; ++i) {
            bool a = (alive[i] != 0);
            __syncthreads();          // all read alive[i] before thread0 clears it
            if (a) {
                if (tid == 0) { keepc[nkeep++] = scf[i]; alive[i] = 0; }
                float px1 = sx1[i], py1 = sy1[i], px2 = sx2[i], py2 = sy2[i];
                float a1 = ((px2 - px1) + 1.0f) * ((py2 - py1) + 1.0f);
                for (int j = i + 1 + tid; j < k; j += NTHR) {
                    if (!alive[j]) continue;
                    float ix1 = fmaxf(px1, sx1[j]);
                    float iy1 = fmaxf(py1, sy1[j]);
                    float ix2 = fminf(px2, sx2[j]);
                    float iy2 = fminf(py2, sy2[j]);
                    float iw = fmaxf((ix2 - ix1) + 1.0f, 0.0f);
                    float ih = fmaxf((iy2 - iy1) + 1.0f, 0.0f);
                    float inter = iw * ih;
                    float a2 = ((sx2[j] - sx1[j]) + 1.0f) * ((sy2[j] - sy1[j]) + 1.0f);
                    float den = ((a1 + a2) - inter) + 1e-16f;
                    if (inter / den > NMS_T) alive[j] = 0;
                }
            }
            __syncthreads();          // suppression visible before next iteration
        }

        if (tid == 0) base = atomicAdd(&counters[CTR_SURV], nkeep);
        __syncthreads();
        int nb = nkeep, b = base;
        for (int i = tid; i < nb; i += NTHR) {
            int o = b + i;
            if (o < SURV_N) AT_STF(&surv[o], keepc[i]);
        }
    }
    grid_bar(bar, 2 * NBLK);

    // ---------------- Phase D: rank-scatter + tail fill ----------------
    // Ranks (ties broken by surv index) form a permutation of 0..m-1, so the
    // scatter covers out[0..m-1] exactly once; fill out[m..OUT_N-1] with NEG.
    {
        int m = AT_LD32((u32*)&counters[CTR_SURV]); if (m > SURV_N) m = SURV_N;
        float* slds = lds;                         // reuse staging LDS (16 KB max)
        for (int i = tid; i < m; i += NTHR) slds[i] = AT_LDF(&surv[i]);
        __syncthreads();

        const int lane = tid & 63;
        const int wid  = gidx >> 6;                      // 0..319
        for (int g = wid; g < m; g += NBLK * (NTHR / 64)) {
            const float v = slds[g];
            int cnt = 0;
            for (int j = lane; j < m; j += 64) {
                float sj = slds[j];
                cnt += (sj > v) || (sj == v && j < g);
            }
            #pragma unroll
            for (int off = 32; off > 0; off >>= 1) cnt += __shfl_down(cnt, off, 64);
            if (lane == 0 && cnt < OUT_N) out[cnt] = v;
        }
        for (int i = m + gidx; i < OUT_N; i += NBLK * NTHR) out[i] = NEGV;
    }
}

extern "C" void kernel_launch(void* const* d_in, const int* in_sizes, int n_in,
                              void* d_out, int out_size, void* d_ws, size_t ws_size,
                              hipStream_t stream) {
    const float* det = (const float*)d_in[0];
    float* out = (float*)d_out;

    const size_t NB = (size_t)N_CLS * KMAX;     // 20480 entries
    char* p = (char*)d_ws;
    int*   counters = (int*)p;  p += 16384;     // 82 spread counters (128B each)
    u64*   pA   = (u64*)p;      p += NB * 8;    // (x1,y1)
    u64*   pB   = (u64*)p;      p += NB * 8;    // (x2,y2)
    u64*   pS   = (u64*)p;      p += NB * 8;    // (score, idx)
    u32*   pC   = (u32*)p;      p += NB * 4;    // conf
    float* surv = (float*)p;                    // SURV_N floats

    hipMemsetAsync(d_ws, 0, CTR_BYTES, stream);   // counters + barrier, every call
    hipLaunchKernelGGL(k_fused, dim3(NBLK), dim3(NTHR), 0, stream,
                       det, out, counters, pA, pB, pS, pC, surv);
}